// Round 11
// baseline (937.538 us; speedup 1.0000x reference)
//
#include <hip/hip_runtime.h>
#include <stdint.h>

// ---------------------------------------------------------------------------
// TransformerBlock: rmsnorm -> QKV -> RoPE -> causal flash attn -> +x ->
//                   rmsnorm -> swiglu FFN -> +O
// bf16 MFMA everywhere; Q/K path uses hi/lo bf16 split (3-pass MFMA).
// R17: flash_k grid (8,64)->(16,64), ONE q-tile per block, longest-first
//      (qt = 15 - blockIdx.x). R16 post-mortem: LDS 51.2KB allows 3 blocks/CU
//      but grid 512 blocks = 2/CU exactly -> occupancy stayed 21%. 1024
//      blocks + LPT ordering lets the CU run 3 blocks with short-tile
//      backfill. Body identical to R16 (verified ledger is per-qt).
// R16: (a) flash_k K single-buffered (K(kt+1) staged mid-iter post-QK-bar;
//      V dbuf). LDS 66->51.2KB. 3 barriers/iter. FIFO: bar -> V(kt+1)[2] ->
//      vmcnt(2) -> bar -> QK -> bar -> K(kt+1)[4] -> softmax/PV.
//      (b) cvt_all_k merges 5 cvt launches + cs_tab (16 -> 11 kernels).
// R15: flash_k denominator via MFMA-with-ones (ls2 = mfma(P, ones));
//      deleted the 16-lane shfl-sum. 183->153us, VGPR 124. Verified.
// R14: RoPE table (cs_tab [2048][32]) + table-lookup epilogue in
//      gemm_split256_k (R13's 128 sincosf/thread was a +50us regression).
// R12/R13: RoPE fused into gemm_split256_k epilogue; rope_k deleted.
//      flash_k P-write via v_cvt_pk_bf16_f32.
// R11/R10: flash_k = R8 body (VGPR pinned ~128; R9's defer-max +28 VGPR
//      halved occupancy -> reverted).
// R9: gemm_split256_k - QKV split GEMM on 256x256 4-phase schedule (neutral).
// R8: gemm256_k 256x256 4-phase for w1/w3; swiglu fused into w3 epilogue;
//     V^T via operand swap (Vt = Wv @ Xn^T).
// R7: flash_k K/V LDS dbuf + counted vmcnt prefetch, raw s_barriers,
//     wave-private P, diag-only masking, exp2 fold, setprio. (240->182us.)
// ---------------------------------------------------------------------------

typedef short bf16x8 __attribute__((ext_vector_type(8)));
typedef float f32x4  __attribute__((ext_vector_type(4)));

#define DEV static __device__ __forceinline__

DEV float bf2f(uint32_t u) { uint32_t v = u << 16; float f; __builtin_memcpy(&f, &v, 4); return f; }
DEV uint16_t f2bf(float f) {
  uint32_t u; __builtin_memcpy(&u, &f, 4);
  u = (u + 0x7fffu + ((u >> 16) & 1u)) >> 16;   // RNE
  return (uint16_t)u;
}

DEV void gl_lds16(const uint16_t* g, uint16_t* l) {
  __builtin_amdgcn_global_load_lds((const __attribute__((address_space(1))) uint32_t*)g,
                                   (__attribute__((address_space(3))) uint32_t*)l, 16, 0, 0);
}

// ------------------- merged weight conversion + RoPE table ------------------
// blocks [0,1024) v_w; [1024,2048) o_w; [2048,6144) w1; [6144,10240) w3;
// [10240,14336) w2; [14336,14592) cos/sin table [2048 pos][32 d2].

__global__ __launch_bounds__(256) void cvt_all_k(
    const float* __restrict__ v_w, const float* __restrict__ o_w,
    const float* __restrict__ w1, const float* __restrict__ w3,
    const float* __restrict__ w2, const int* __restrict__ pos,
    uint16_t* __restrict__ wv, uint16_t* __restrict__ wo,
    uint16_t* __restrict__ w1b, uint16_t* __restrict__ w3b,
    uint16_t* __restrict__ w2b, float2* __restrict__ cstab) {
  const int b = blockIdx.x;
  if (b >= 14336) {
    const int t = (b - 14336) * 256 + threadIdx.x;   // 2048*32
    const int p = t >> 5, d2 = t & 31;
    const float inv_freq = exp2f((float)d2 * -0.41524101186092029f);
    float sn, cs; sincosf((float)pos[p] * inv_freq, &sn, &cs);
    cstab[t] = make_float2(cs, sn);
    return;
  }
  const float* src; uint16_t* dst; int t;
  if (b < 1024)       { src = v_w; dst = wv;  t = b * 256 + threadIdx.x; }
  else if (b < 2048)  { src = o_w; dst = wo;  t = (b - 1024) * 256 + threadIdx.x; }
  else if (b < 6144)  { src = w1;  dst = w1b; t = (b - 2048) * 256 + threadIdx.x; }
  else if (b < 10240) { src = w3;  dst = w3b; t = (b - 6144) * 256 + threadIdx.x; }
  else                { src = w2;  dst = w2b; t = (b - 10240) * 256 + threadIdx.x; }
  const float4 v = ((const float4*)src)[t];
  ushort4 o; o.x = f2bf(v.x); o.y = f2bf(v.y); o.z = f2bf(v.z); o.w = f2bf(v.w);
  ((ushort4*)dst)[t] = o;
}

__global__ __launch_bounds__(256) void cvt_split_qk_k(const float* __restrict__ qw,
                                                      const float* __restrict__ kw,
                                                      uint16_t* __restrict__ hi,
                                                      uint16_t* __restrict__ lo) {
  const int t = blockIdx.x * 256 + threadIdx.x;    // 2048*256 float4s
  const int row = t >> 8, c4 = t & 255;
  const float* src = (row < 1024) ? (qw + (size_t)row * 1024)
                                  : (kw + (size_t)(row - 1024) * 1024);
  const float4 v = ((const float4*)src)[c4];
  ushort4 h, l;
  h.x = f2bf(v.x); l.x = f2bf(v.x - bf2f(h.x));
  h.y = f2bf(v.y); l.y = f2bf(v.y - bf2f(h.y));
  h.z = f2bf(v.z); l.z = f2bf(v.z - bf2f(h.z));
  h.w = f2bf(v.w); l.w = f2bf(v.w - bf2f(h.w));
  ((ushort4*)hi)[t] = h; ((ushort4*)lo)[t] = l;
}

// -------------------------------- rmsnorm ----------------------------------

template <bool SPLIT>
__global__ __launch_bounds__(256) void rmsnorm_k(const float* __restrict__ xin,
                                                 const float* __restrict__ g,
                                                 uint16_t* __restrict__ hi,
                                                 uint16_t* __restrict__ lo) {
  const int row = blockIdx.x, t = threadIdx.x;
  const float4 v = ((const float4*)(xin + (size_t)row * 1024))[t];
  float ss = v.x * v.x + v.y * v.y + v.z * v.z + v.w * v.w;
#pragma unroll
  for (int m = 1; m < 64; m <<= 1) ss += __shfl_xor(ss, m);
  __shared__ float red[4];
  if ((t & 63) == 0) red[t >> 6] = ss;
  __syncthreads();
  const float rinv = rsqrtf((red[0] + red[1] + red[2] + red[3]) * (1.0f / 1024.0f) + 1e-5f);
  const float4 gv = ((const float4*)g)[t];
  float y[4] = { v.x * rinv * gv.x, v.y * rinv * gv.y, v.z * rinv * gv.z, v.w * rinv * gv.w };
  ushort4 h; h.x = f2bf(y[0]); h.y = f2bf(y[1]); h.z = f2bf(y[2]); h.w = f2bf(y[3]);
  ((ushort4*)(hi + (size_t)row * 1024))[t] = h;
  if constexpr (SPLIT) {
    ushort4 l;
    l.x = f2bf(y[0] - bf2f(h.x)); l.y = f2bf(y[1] - bf2f(h.y));
    l.z = f2bf(y[2] - bf2f(h.z)); l.w = f2bf(y[3] - bf2f(h.w));
    ((ushort4*)(lo + (size_t)row * 1024))[t] = l;
  }
}

// ------------------------ GEMM  C[M,N] = A[M,K] @ B[N,K]^T ------------------
// 128x128 tile, BK=64, 4 waves (2x2), 16x16x32 bf16 MFMA.
// LDS tiles XOR-swizzled: slot [r][g] holds global colgrp g^(r&7).

template <int OUT>   // 0: bf16 out; 1: f32 out + residual add
__global__ __launch_bounds__(256) void gemm_bt_k(const uint16_t* __restrict__ A,
                                                 const uint16_t* __restrict__ B,
                                                 void* __restrict__ C,
                                                 const float* __restrict__ resid,
                                                 int N, int K) {
  __shared__ __align__(16) uint16_t As[128 * 64];
  __shared__ __align__(16) uint16_t Bs[128 * 64];
  const int t = threadIdx.x, w = t >> 6, lane = t & 63, m16 = lane & 15, quad = lane >> 4;
  const int wm = (w >> 1) * 64, wn = (w & 1) * 64;
  const int mBase = blockIdx.y * 128, nBase = blockIdx.x * 128;
  f32x4 acc[4][4];
  const f32x4 vz = {0.f, 0.f, 0.f, 0.f};
#pragma unroll
  for (int i = 0; i < 4; ++i)
#pragma unroll
    for (int j = 0; j < 4; ++j) acc[i][j] = vz;
  const int r_ = t >> 3, g_ = t & 7, sg = g_ ^ (r_ & 7);   // (it*32) % 8 == 0
  const uint16_t* ag = A + (size_t)(mBase + r_) * K + sg * 8;
  const uint16_t* bg = B + (size_t)(nBase + r_) * K + sg * 8;
  for (int k0 = 0; k0 < K; k0 += 64) {
#pragma unroll
    for (int it = 0; it < 4; ++it) {
      gl_lds16(ag + (size_t)(it * 32) * K + k0, As + it * 2048 + t * 8);
      gl_lds16(bg + (size_t)(it * 32) * K + k0, Bs + it * 2048 + t * 8);
    }
    __syncthreads();
#pragma unroll
    for (int ks = 0; ks < 2; ++ks) {
      bf16x8 af[4], bf4[4];
      const int cg = ks * 4 + quad;
#pragma unroll
      for (int i = 0; i < 4; ++i) {
        const int rA = wm + i * 16 + m16;
        af[i] = *(const bf16x8*)(As + rA * 64 + ((cg ^ (rA & 7)) * 8));
        const int rB = wn + i * 16 + m16;
        bf4[i] = *(const bf16x8*)(Bs + rB * 64 + ((cg ^ (rB & 7)) * 8));
      }
#pragma unroll
      for (int i = 0; i < 4; ++i)
#pragma unroll
        for (int j = 0; j < 4; ++j)
          acc[i][j] = __builtin_amdgcn_mfma_f32_16x16x32_bf16(af[i], bf4[j], acc[i][j], 0, 0, 0);
    }
    __syncthreads();
  }
#pragma unroll
  for (int i = 0; i < 4; ++i) {
    const int row0 = mBase + wm + i * 16 + quad * 4;
#pragma unroll
    for (int j = 0; j < 4; ++j) {
      const int col = nBase + wn + j * 16 + m16;
#pragma unroll
      for (int r = 0; r < 4; ++r) {
        const size_t idx = (size_t)(row0 + r) * N + col;
        const float v = acc[i][j][r];
        if constexpr (OUT == 1) ((float*)C)[idx] = v + resid[idx];
        else                    ((uint16_t*)C)[idx] = f2bf(v);
      }
    }
  }
}

// -------------- 256x256 8-phase GEMM  C[M,N] = A[M,K] @ B[N,K]^T ------------
// BK=64, 512 thr = 8 waves (2M x 4N), per-wave 128x64 out = acc[8][4].
// LDS: A/B double-buffered 256x64 each = 128 KiB. Stage 2 tiles ahead,
// 1 half-tile (2 gl_lds) per phase; vmcnt(6) once per K-tile (phase 0).

template <int OUT>   // 0: bf16 store; 2: bf16 store of silu(aux)*acc (fused swiglu)
__global__ __launch_bounds__(512, 2) void gemm256_k(const uint16_t* __restrict__ A,
                                                    const uint16_t* __restrict__ B,
                                                    uint16_t* __restrict__ C,
                                                    const uint16_t* __restrict__ aux,
                                                    int N, int K) {
  __shared__ __align__(16) uint16_t As[2][256 * 64];
  __shared__ __align__(16) uint16_t Bs[2][256 * 64];
  const int t = threadIdx.x, w = t >> 6, lane = t & 63, m16 = lane & 15, quad = lane >> 4;
  const int wm = (w >> 2) * 128, wn = (w & 3) * 64;
  const int mBase = blockIdx.y * 256, nBase = blockIdx.x * 256;
  const int NT = K >> 6;

  f32x4 acc[8][4];
  const f32x4 vz = {0.f, 0.f, 0.f, 0.f};
#pragma unroll
  for (int i = 0; i < 8; ++i)
#pragma unroll
    for (int j = 0; j < 4; ++j) acc[i][j] = vz;

  const int r_ = t >> 3, g_ = t & 7, sg = g_ ^ (r_ & 7);   // 64-row chunks keep (row&7)
  const uint16_t* ag = A + (size_t)(mBase + r_) * K + sg * 8;
  const uint16_t* bg = B + (size_t)(nBase + r_) * K + sg * 8;

#define STG_A(kt, h)                                                         \
  if ((kt) < NT) {                                                           \
    uint16_t* d0 = &As[(kt) & 1][(h) * 8192 + t * 8];                        \
    const uint16_t* s0 = ag + (size_t)((h) * 128) * K + (kt) * 64;           \
    gl_lds16(s0, d0);                                                        \
    gl_lds16(s0 + (size_t)64 * K, d0 + 4096);                                \
  }
#define STG_B(kt, h)                                                         \
  if ((kt) < NT) {                                                           \
    uint16_t* d0 = &Bs[(kt) & 1][(h) * 8192 + t * 8];                        \
    const uint16_t* s0 = bg + (size_t)((h) * 128) * K + (kt) * 64;           \
    gl_lds16(s0, d0);                                                        \
    gl_lds16(s0 + (size_t)64 * K, d0 + 4096);                                \
  }

  // prologue: tile0 fully + tile1's Bh0/Ah0 (oldest-first for vmcnt math)
  STG_B(0, 0); STG_B(0, 1); STG_A(0, 0); STG_A(0, 1);
  STG_B(1, 0); STG_A(1, 0);

  for (int T = 0; T < NT; ++T) {
    const int c = T & 1;
    const uint16_t* Ac = As[c];
    const uint16_t* Bc = Bs[c];
    bf16x8 af[4][2], b0[2][2], b1[2][2];

    // ---------------- ph0: quadrant (mq0, nq0) ----------------
    STG_B(T + 1, 1);
    if (T == NT - 1) { asm volatile("s_waitcnt vmcnt(0)" ::: "memory"); }
    else             { asm volatile("s_waitcnt vmcnt(6)" ::: "memory"); }
    __builtin_amdgcn_s_barrier();
    __builtin_amdgcn_sched_barrier(0);
#pragma unroll
    for (int i = 0; i < 4; ++i) {
      const int rA = wm + i * 16 + m16;
#pragma unroll
      for (int ks = 0; ks < 2; ++ks)
        af[i][ks] = *(const bf16x8*)(Ac + rA * 64 + (((ks * 4 + quad) ^ (rA & 7)) * 8));
    }
#pragma unroll
    for (int j = 0; j < 2; ++j) {
      const int rB = wn + j * 16 + m16;
#pragma unroll
      for (int ks = 0; ks < 2; ++ks)
        b0[j][ks] = *(const bf16x8*)(Bc + rB * 64 + (((ks * 4 + quad) ^ (rB & 7)) * 8));
    }
    __builtin_amdgcn_s_setprio(1);
#pragma unroll
    for (int ks = 0; ks < 2; ++ks)
#pragma unroll
      for (int i = 0; i < 4; ++i)
#pragma unroll
        for (int j = 0; j < 2; ++j)
          acc[i][j] = __builtin_amdgcn_mfma_f32_16x16x32_bf16(af[i][ks], b0[j][ks], acc[i][j], 0, 0, 0);
    __builtin_amdgcn_s_setprio(0);
    __builtin_amdgcn_s_barrier();

    // ---------------- ph1: (mq0, nq1) ----------------
    STG_A(T + 1, 1);
#pragma unroll
    for (int j = 0; j < 2; ++j) {
      const int rB = wn + (2 + j) * 16 + m16;
#pragma unroll
      for (int ks = 0; ks < 2; ++ks)
        b1[j][ks] = *(const bf16x8*)(Bc + rB * 64 + (((ks * 4 + quad) ^ (rB & 7)) * 8));
    }
    __builtin_amdgcn_s_setprio(1);
#pragma unroll
    for (int ks = 0; ks < 2; ++ks)
#pragma unroll
      for (int i = 0; i < 4; ++i)
#pragma unroll
        for (int j = 0; j < 2; ++j)
          acc[i][2 + j] = __builtin_amdgcn_mfma_f32_16x16x32_bf16(af[i][ks], b1[j][ks], acc[i][2 + j], 0, 0, 0);
    __builtin_amdgcn_s_setprio(0);
    __builtin_amdgcn_s_barrier();

    // ---------------- ph2: (mq1, nq0) ----------------
    STG_B(T + 2, 0);
#pragma unroll
    for (int i = 0; i < 4; ++i) {
      const int rA = wm + 64 + i * 16 + m16;
#pragma unroll
      for (int ks = 0; ks < 2; ++ks)
        af[i][ks] = *(const bf16x8*)(Ac + rA * 64 + (((ks * 4 + quad) ^ (rA & 7)) * 8));
    }
    __builtin_amdgcn_s_setprio(1);
#pragma unroll
    for (int ks = 0; ks < 2; ++ks)
#pragma unroll
      for (int i = 0; i < 4; ++i)
#pragma unroll
        for (int j = 0; j < 2; ++j)
          acc[4 + i][j] = __builtin_amdgcn_mfma_f32_16x16x32_bf16(af[i][ks], b0[j][ks], acc[4 + i][j], 0, 0, 0);
    __builtin_amdgcn_s_setprio(0);
    __builtin_amdgcn_s_barrier();

    // ---------------- ph3: (mq1, nq1) ----------------
    STG_A(T + 2, 0);
    __builtin_amdgcn_s_setprio(1);
#pragma unroll
    for (int ks = 0; ks < 2; ++ks)
#pragma unroll
      for (int i = 0; i < 4; ++i)
#pragma unroll
        for (int j = 0; j < 2; ++j)
          acc[4 + i][2 + j] = __builtin_amdgcn_mfma_f32_16x16x32_bf16(af[i][ks], b1[j][ks], acc[4 + i][2 + j], 0, 0, 0);
    __builtin_amdgcn_s_setprio(0);
    __builtin_amdgcn_s_barrier();
  }
#undef STG_A
#undef STG_B

#pragma unroll
  for (int i = 0; i < 8; ++i) {
    const int row0 = mBase + wm + i * 16 + quad * 4;
#pragma unroll
    for (int j = 0; j < 4; ++j) {
      const int col = nBase + wn + j * 16 + m16;
#pragma unroll
      for (int r = 0; r < 4; ++r) {
        const size_t idx = (size_t)(row0 + r) * N + col;
        const float v = acc[i][j][r];
        if constexpr (OUT == 2) {
          const float a = bf2f(aux[idx]);
          const float sw = a / (1.f + __expf(-a));
          C[idx] = f2bf(sw * v);
        } else {
          C[idx] = f2bf(v);
        }
      }
    }
  }
}

// -------- 256x256 4-phase split-precision GEMM (Q/K projection), BK=32 -----
// acc += Ahi*Bhi + Ahi*Blo + Alo*Bhi  (drops lo*lo: ~2^-18 relative)
// 512 thr = 8 waves (2M x 4N), per-wave 128x64 = acc[8][4]; 24 MFMA/phase.
// LDS: Ah/Al/Bh/Bl dbuf 256x32 each = 128 KiB.
// Stage stream: ph0->AH(T+1), ph1->AL(T+1), ph2->BH(T+2), ph3->BL(T+2).
// vmcnt(6) at ph0: FIFO = [B(T)4, AH(T)2, AL(T)2, B(T+1)4, AH(T+1)2] ->
// keep newest 6, drain tile T's 8. Prologue order B(0),A(0),B(1) matches.
// R12: RoPE fused in the epilogue - adjacent (even,odd) columns live in
// adjacent lanes, one __shfl_xor(v,1) pairs them; rotate fp32, then split.
// R14: cos/sin from precomputed table (cached 8B loads) - no sincosf here.

__global__ __launch_bounds__(512, 2) void gemm_split256_k(
    const uint16_t* __restrict__ Ahi, const uint16_t* __restrict__ Alo,
    const uint16_t* __restrict__ Bhi, const uint16_t* __restrict__ Blo,
    uint16_t* __restrict__ Chi, uint16_t* __restrict__ Clo,
    const float2* __restrict__ cstab, int N, int K) {
  __shared__ __align__(16) uint16_t Ah[2][256 * 32];
  __shared__ __align__(16) uint16_t Al[2][256 * 32];
  __shared__ __align__(16) uint16_t Bh[2][256 * 32];
  __shared__ __align__(16) uint16_t Bl[2][256 * 32];
  const int t = threadIdx.x, w = t >> 6, lane = t & 63, m16 = lane & 15, quad = lane >> 4;
  const int wm = (w >> 2) * 128, wn = (w & 3) * 64;
  const int mBase = blockIdx.y * 256, nBase = blockIdx.x * 256;
  const int NT = K >> 5;

  f32x4 acc[8][4];
  const f32x4 vz = {0.f, 0.f, 0.f, 0.f};
#pragma unroll
  for (int i = 0; i < 8; ++i)
#pragma unroll
    for (int j = 0; j < 4; ++j) acc[i][j] = vz;

  const int r_ = t >> 2, g_ = t & 3, sg = g_ ^ (r_ & 3);   // rows stack by 128: (r&3) kept
  const uint16_t* agh = Ahi + (size_t)(mBase + r_) * K + sg * 8;
  const uint16_t* agl = Alo + (size_t)(mBase + r_) * K + sg * 8;
  const uint16_t* bgh = Bhi + (size_t)(nBase + r_) * K + sg * 8;
  const uint16_t* bgl = Blo + (size_t)(nBase + r_) * K + sg * 8;

  // one operand, one K-tile = 256x32 = 16KB = 2 issues (rows 0-127, 128-255)
#define STG4(OP, base, kt)                                                   \
  if ((kt) < NT) {                                                           \
    uint16_t* d = &OP[(kt) & 1][t * 8];                                      \
    const uint16_t* s = (base) + (size_t)(kt) * 32;                          \
    gl_lds16(s, d);                                                          \
    gl_lds16(s + (size_t)128 * K, d + 4096);                                 \
  }

  // prologue (FIFO order = steady-state expectation for T=0)
  STG4(Bh, bgh, 0); STG4(Bl, bgl, 0);
  STG4(Ah, agh, 0); STG4(Al, agl, 0);
  STG4(Bh, bgh, 1); STG4(Bl, bgl, 1);

  for (int T = 0; T < NT; ++T) {
    const int c = T & 1;
    bf16x8 a_h[4], a_l[4], b0h[2], b0l[2], b1h[2], b1l[2];

    // ---------------- ph0: (mq0, nq0) ----------------
    STG4(Ah, agh, T + 1);
    if (T == NT - 1) { asm volatile("s_waitcnt vmcnt(0)" ::: "memory"); }
    else             { asm volatile("s_waitcnt vmcnt(6)" ::: "memory"); }
    __builtin_amdgcn_s_barrier();
    __builtin_amdgcn_sched_barrier(0);
#pragma unroll
    for (int i = 0; i < 4; ++i) {
      const int rA = wm + i * 16 + m16;
      const int offA = rA * 32 + ((quad ^ (rA & 3)) * 8);
      a_h[i] = *(const bf16x8*)(&Ah[c][offA]);
      a_l[i] = *(const bf16x8*)(&Al[c][offA]);
    }
#pragma unroll
    for (int j = 0; j < 2; ++j) {
      const int rB = wn + j * 16 + m16;
      const int offB = rB * 32 + ((quad ^ (rB & 3)) * 8);
      b0h[j] = *(const bf16x8*)(&Bh[c][offB]);
      b0l[j] = *(const bf16x8*)(&Bl[c][offB]);
    }
    __builtin_amdgcn_s_setprio(1);
#pragma unroll
    for (int i = 0; i < 4; ++i)
#pragma unroll
      for (int j = 0; j < 2; ++j) {
        acc[i][j] = __builtin_amdgcn_mfma_f32_16x16x32_bf16(a_h[i], b0h[j], acc[i][j], 0, 0, 0);
        acc[i][j] = __builtin_amdgcn_mfma_f32_16x16x32_bf16(a_h[i], b0l[j], acc[i][j], 0, 0, 0);
        acc[i][j] = __builtin_amdgcn_mfma_f32_16x16x32_bf16(a_l[i], b0h[j], acc[i][j], 0, 0, 0);
      }
    __builtin_amdgcn_s_setprio(0);
    __builtin_amdgcn_s_barrier();

    // ---------------- ph1: (mq0, nq1) ----------------
    STG4(Al, agl, T + 1);
#pragma unroll
    for (int j = 0; j < 2; ++j) {
      const int rB = wn + (2 + j) * 16 + m16;
      const int offB = rB * 32 + ((quad ^ (rB & 3)) * 8);
      b1h[j] = *(const bf16x8*)(&Bh[c][offB]);
      b1l[j] = *(const bf16x8*)(&Bl[c][offB]);
    }
    __builtin_amdgcn_s_setprio(1);
#pragma unroll
    for (int i = 0; i < 4; ++i)
#pragma unroll
      for (int j = 0; j < 2; ++j) {
        acc[i][2 + j] = __builtin_amdgcn_mfma_f32_16x16x32_bf16(a_h[i], b1h[j], acc[i][2 + j], 0, 0, 0);
        acc[i][2 + j] = __builtin_amdgcn_mfma_f32_16x16x32_bf16(a_h[i], b1l[j], acc[i][2 + j], 0, 0, 0);
        acc[i][2 + j] = __builtin_amdgcn_mfma_f32_16x16x32_bf16(a_l[i], b1h[j], acc[i][2 + j], 0, 0, 0);
      }
    __builtin_amdgcn_s_setprio(0);
    __builtin_amdgcn_s_barrier();

    // ---------------- ph2: (mq1, nq0) ----------------
    STG4(Bh, bgh, T + 2);
#pragma unroll
    for (int i = 0; i < 4; ++i) {
      const int rA = wm + 64 + i * 16 + m16;
      const int offA = rA * 32 + ((quad ^ (rA & 3)) * 8);
      a_h[i] = *(const bf16x8*)(&Ah[c][offA]);
      a_l[i] = *(const bf16x8*)(&Al[c][offA]);
    }
    __builtin_amdgcn_s_setprio(1);
#pragma unroll
    for (int i = 0; i < 4; ++i)
#pragma unroll
      for (int j = 0; j < 2; ++j) {
        acc[4 + i][j] = __builtin_amdgcn_mfma_f32_16x16x32_bf16(a_h[i], b0h[j], acc[4 + i][j], 0, 0, 0);
        acc[4 + i][j] = __builtin_amdgcn_mfma_f32_16x16x32_bf16(a_h[i], b0l[j], acc[4 + i][j], 0, 0, 0);
        acc[4 + i][j] = __builtin_amdgcn_mfma_f32_16x16x32_bf16(a_l[i], b0h[j], acc[4 + i][j], 0, 0, 0);
      }
    __builtin_amdgcn_s_setprio(0);
    __builtin_amdgcn_s_barrier();

    // ---------------- ph3: (mq1, nq1) ----------------
    STG4(Bl, bgl, T + 2);
    __builtin_amdgcn_s_setprio(1);
#pragma unroll
    for (int i = 0; i < 4; ++i)
#pragma unroll
      for (int j = 0; j < 2; ++j) {
        acc[4 + i][2 + j] = __builtin_amdgcn_mfma_f32_16x16x32_bf16(a_h[i], b1h[j], acc[4 + i][2 + j], 0, 0, 0);
        acc[4 + i][2 + j] = __builtin_amdgcn_mfma_f32_16x16x32_bf16(a_h[i], b1l[j], acc[4 + i][2 + j], 0, 0, 0);
        acc[4 + i][2 + j] = __builtin_amdgcn_mfma_f32_16x16x32_bf16(a_l[i], b1h[j], acc[4 + i][2 + j], 0, 0, 0);
      }
    __builtin_amdgcn_s_setprio(0);
    __builtin_amdgcn_s_barrier();
  }
#undef STG4

  // ---- epilogue: fused RoPE (table-driven, fp32) + hi/lo split store ----
  int d2v[4];
#pragma unroll
  for (int j = 0; j < 4; ++j)
    d2v[j] = ((nBase + wn + j * 16 + m16) & 63) >> 1;
  const bool oddc = (m16 & 1) != 0;
#pragma unroll
  for (int i = 0; i < 8; ++i) {
    const int row0 = mBase + wm + i * 16 + quad * 4;
#pragma unroll
    for (int r = 0; r < 4; ++r) {
      const int row = row0 + r;
      const float2* crow = cstab + (size_t)(row & 2047) * 32;
      const size_t rb = (size_t)row * N;
#pragma unroll
      for (int j = 0; j < 4; ++j) {
        const float v = acc[i][j][r];
        const float pv = __shfl_xor(v, 1);      // partner column's value
        const float xe = oddc ? pv : v;
        const float xo = oddc ? v : pv;
        const float2 cs = crow[d2v[j]];         // (cos, sin)
        const float vr = oddc ? (xe * cs.y + xo * cs.x) : (xe * cs.x - xo * cs.y);
        const size_t idx = rb + (nBase + wn + j * 16 + m16);
        const uint16_t hh = f2bf(vr);
        Chi[idx] = hh;
        Clo[idx] = f2bf(vr - bf2f(hh));
      }
    }
  }
}

// ----------------------- causal flash attention -----------------------------
// R17: grid (16,64), ONE q-tile per block, longest-first (qt = 15 - bx) so
// 32-iter diagonal blocks dispatch first; short blocks backfill (LPT).
// R16 schedule (K single-buffered, V double-buffered; 3 barriers/iter):
//   prologue: stage K(0)[4 DMA] then V(0)[2 DMA] into Vs[0].
//   iter kt: bar(guard: Vs[nxt] free) -> issue V(kt+1)->Vs[nxt] ->
//            vmcnt(2) [K(kt)+V(kt) done; V(kt+1) in flight] -> bar ->
//            QK MFMA on K LDS -> bar(K reads done) -> issue K(kt+1) ->
//            softmax -> P write -> PV on Vs[cur].
// LDS 51.2KB (Kh 8K + Kl 8K + Vs 16K + P 18.4K) -> 3 blocks/CU.
// R15: denominator via MFMA-with-ones. R12: cvt_pk P-write. VGPR ~124 - DO
// NOT grow registers (R9 lesson).
// Vt layout [1024 d-rows][8192 tokens] (stride 8192, col b*2048+s).

__global__ __launch_bounds__(256) void flash_k(const uint16_t* __restrict__ Qh,
                                               const uint16_t* __restrict__ Ql,
                                               const uint16_t* __restrict__ Vt,
                                               uint16_t* __restrict__ Hout) {
  __shared__ __align__(16) uint16_t Kh[64 * 64];
  __shared__ __align__(16) uint16_t Kl[64 * 64];
  __shared__ __align__(16) uint16_t Vs[2][64 * 64];
  __shared__ __align__(16) uint16_t P[4][32 * 72];

  const int bh = blockIdx.y, b = bh >> 4, h = bh & 15;
  const int t = threadIdx.x, w = t >> 6, lane = t & 63, m16 = lane & 15, quad = lane >> 4;

  const int r_ = t >> 3, g_ = t & 7, sgx = g_ ^ (r_ & 7);
  const uint16_t* khg = Qh + (size_t)(b * 2048 + r_) * 2048 + 1024 + h * 64 + sgx * 8;
  const uint16_t* klg = Ql + (size_t)(b * 2048 + r_) * 2048 + 1024 + h * 64 + sgx * 8;
  const uint16_t* vtg = Vt + (size_t)(h * 64 + r_) * 8192 + (size_t)b * 2048 + sgx * 8;

  const float nscl = 0.18033688011112042f;   // log2(e)/8: fold 1/sqrt(64) + ln->log2
  bf16x8 onef;
#pragma unroll
  for (int e = 0; e < 8; ++e) onef[e] = (short)0x3F80;   // bf16 1.0

  // longest-job-first: bx=0 -> qt=15 (32 KV-iters) dispatches earliest.
  const int qt = 15 - (int)blockIdx.x;

  bf16x8 qh[2][2], ql[2][2];
#pragma unroll
  for (int i = 0; i < 2; ++i) {
    const int row = b * 2048 + qt * 128 + w * 32 + i * 16 + m16;
#pragma unroll
    for (int ks = 0; ks < 2; ++ks) {
      const size_t offq = (size_t)row * 2048 + h * 64 + ks * 32 + quad * 8;
      qh[i][ks] = *(const bf16x8*)(Qh + offq);
      ql[i][ks] = *(const bf16x8*)(Ql + offq);
    }
  }
  // Pin Q fragments: forces the compiler's vmcnt drain HERE, so inside the
  // loop the outstanding-VMEM count is exactly our DMA loads.
#pragma unroll
  for (int i = 0; i < 2; ++i)
#pragma unroll
    for (int ks = 0; ks < 2; ++ks)
      asm volatile("" : "+v"(qh[i][ks]), "+v"(ql[i][ks]));

  const int ktEnd = 2 * qt + 2;

  // prologue: K(0) [4 DMA] then V(0) [2 DMA] (FIFO order for vmcnt math)
#pragma unroll
  for (int it = 0; it < 2; ++it) {
    gl_lds16(khg + (size_t)(it * 32) * 2048, &Kh[it * 2048 + t * 8]);
    gl_lds16(klg + (size_t)(it * 32) * 2048, &Kl[it * 2048 + t * 8]);
  }
#pragma unroll
  for (int it = 0; it < 2; ++it)
    gl_lds16(vtg + (size_t)(it * 32) * 8192, &Vs[0][it * 2048 + t * 8]);

  float mr[2][4];
  f32x4 o[2][4], ls2[2];
  const f32x4 vz = {0.f, 0.f, 0.f, 0.f};
#pragma unroll
  for (int i = 0; i < 2; ++i)
#pragma unroll
    for (int r = 0; r < 4; ++r) mr[i][r] = -1e30f;
  ls2[0] = vz; ls2[1] = vz;
#pragma unroll
  for (int i = 0; i < 2; ++i)
#pragma unroll
    for (int n = 0; n < 4; ++n) o[i][n] = vz;

  for (int kt = 0; kt < ktEnd; ++kt) {
    const int cur = kt & 1, nxt = cur ^ 1;
    // bar 1 (guard): all waves finished PV(kt-1) reads of Vs[nxt].
    __builtin_amdgcn_s_barrier();
    __builtin_amdgcn_sched_barrier(0);
    if (kt + 1 < ktEnd) {
#pragma unroll
      for (int it = 0; it < 2; ++it)
        gl_lds16(vtg + (size_t)(it * 32) * 8192 + (kt + 1) * 64,
                 &Vs[nxt][it * 2048 + t * 8]);
      // K(kt)[4] + V(kt)[2] must be done; keep V(kt+1)[2] in flight.
      asm volatile("s_waitcnt vmcnt(2)" ::: "memory");
    } else {
      asm volatile("s_waitcnt vmcnt(0)" ::: "memory");
    }
    // bar 2: K(kt)/V(kt) LDS data visible to all waves.
    __builtin_amdgcn_s_barrier();
    __builtin_amdgcn_sched_barrier(0);

    // ---- QK^T (3-pass hi/lo) on the single K buffer ----
    f32x4 sc[2][4];
#pragma unroll
    for (int i = 0; i < 2; ++i)
#pragma unroll
      for (int j = 0; j < 4; ++j) sc[i][j] = vz;
#pragma unroll
    for (int ks = 0; ks < 2; ++ks) {
      bf16x8 kfh[4], kfl[4];
      const int cg = ks * 4 + quad;
#pragma unroll
      for (int j = 0; j < 4; ++j) {
        const int rK = j * 16 + m16;
        const int offk = rK * 64 + ((cg ^ (rK & 7)) * 8);
        kfh[j] = *(const bf16x8*)(&Kh[offk]);
        kfl[j] = *(const bf16x8*)(&Kl[offk]);
      }
      __builtin_amdgcn_s_setprio(1);
#pragma unroll
      for (int i = 0; i < 2; ++i)
#pragma unroll
        for (int j = 0; j < 4; ++j) {
          sc[i][j] = __builtin_amdgcn_mfma_f32_16x16x32_bf16(qh[i][ks], kfh[j], sc[i][j], 0, 0, 0);
          sc[i][j] = __builtin_amdgcn_mfma_f32_16x16x32_bf16(qh[i][ks], kfl[j], sc[i][j], 0, 0, 0);
          sc[i][j] = __builtin_amdgcn_mfma_f32_16x16x32_bf16(ql[i][ks], kfh[j], sc[i][j], 0, 0, 0);
        }
      __builtin_amdgcn_s_setprio(0);
    }

    // bar 3: all waves' QK LDS reads complete -> K buffer free for kt+1.
    __builtin_amdgcn_s_barrier();
    __builtin_amdgcn_sched_barrier(0);
    if (kt + 1 < ktEnd) {
#pragma unroll
      for (int it = 0; it < 2; ++it) {
        gl_lds16(khg + (size_t)((kt + 1) * 64 + it * 32) * 2048, &Kh[it * 2048 + t * 8]);
        gl_lds16(klg + (size_t)((kt + 1) * 64 + it * 32) * 2048, &Kl[it * 2048 + t * 8]);
      }
    }

    // ---- online softmax, raw-score domain; row-sum comes from the
    //      MFMA-with-ones in the PV phase (R15), not a shfl reduce ----
#pragma unroll
    for (int i = 0; i < 2; ++i) {
      const bool needMask = (kt * 64 + 63) > (qt * 128 + w * 32 + i * 16);
#pragma unroll
      for (int r = 0; r < 4; ++r) {
        float mx = -1e30f;
        if (needMask) {
          const int qg = qt * 128 + w * 32 + i * 16 + quad * 4 + r;
#pragma unroll
          for (int j = 0; j < 4; ++j) {
            float v = sc[i][j][r];
            const int kg = kt * 64 + j * 16 + m16;
            if (kg > qg) v = -1e30f;
            sc[i][j][r] = v;
            mx = fmaxf(mx, v);
          }
        } else {
#pragma unroll
          for (int j = 0; j < 4; ++j) mx = fmaxf(mx, sc[i][j][r]);
        }
#pragma unroll
        for (int m = 1; m < 16; m <<= 1) mx = fmaxf(mx, __shfl_xor(mx, m));
        const float mnew = fmaxf(mr[i][r], mx);
        const float alpha = __builtin_amdgcn_exp2f((mr[i][r] - mnew) * nscl);
        mr[i][r] = mnew;
        const float nm = mnew * nscl;
#pragma unroll
        for (int j = 0; j < 4; ++j)
          sc[i][j][r] = __builtin_amdgcn_exp2f(__builtin_fmaf(sc[i][j][r], nscl, -nm));
        ls2[i][r] *= alpha;
#pragma unroll
        for (int n = 0; n < 4; ++n) o[i][n][r] *= alpha;
      }
      // P-write: HW packed bf16 convert (RNE), then scalar u16 stores (the
      // 4 targets per j are non-adjacent rows - stores were scalar before).
#pragma unroll
      for (int j = 0; j < 4; ++j) {
        uint32_t pk01, pk23;
        asm("v_cvt_pk_bf16_f32 %0, %1, %2"
            : "=v"(pk01) : "v"(sc[i][j][0]), "v"(sc[i][j][1]));
        asm("v_cvt_pk_bf16_f32 %0, %1, %2"
            : "=v"(pk23) : "v"(sc[i][j][2]), "v"(sc[i][j][3]));
        const int pb = (i * 16 + quad * 4) * 72 + j * 16 + m16;
        P[w][pb]       = (uint16_t)pk01;
        P[w][pb + 72]  = (uint16_t)(pk01 >> 16);
        P[w][pb + 144] = (uint16_t)pk23;
        P[w][pb + 216] = (uint16_t)(pk23 >> 16);
      }
    }
    // P[w] is wave-private: intra-wave ds_write->ds_read needs only the
    // compiler-inserted lgkmcnt, no cross-wave barrier.

#pragma unroll
    for (int ks2 = 0; ks2 < 2; ++ks2) {
      bf16x8 pf[2], vf[4];
#pragma unroll
      for (int i = 0; i < 2; ++i)
        pf[i] = *(const bf16x8*)(&P[w][(i * 16 + m16) * 72 + ks2 * 32 + quad * 8]);
      const int cg = ks2 * 4 + quad;
#pragma unroll
      for (int n = 0; n < 4; ++n) {
        const int rV = n * 16 + m16;
        vf[n] = *(const bf16x8*)(&Vs[cur][rV * 64 + ((cg ^ (rV & 7)) * 8)]);
      }
      __builtin_amdgcn_s_setprio(1);
#pragma unroll
      for (int i = 0; i < 2; ++i) {
        // R15: denominator = row-sum of P via MFMA with B = ones
        ls2[i] = __builtin_amdgcn_mfma_f32_16x16x32_bf16(pf[i], onef, ls2[i], 0, 0, 0);
#pragma unroll
        for (int n = 0; n < 4; ++n)
          o[i][n] = __builtin_amdgcn_mfma_f32_16x16x32_bf16(pf[i], vf[n], o[i][n], 0, 0, 0);
      }
      __builtin_amdgcn_s_setprio(0);
    }
  }

#pragma unroll
  for (int i = 0; i < 2; ++i)
#pragma unroll
    for (int r = 0; r < 4; ++r) {
      const float inv = 1.f / ls2[i][r];
      const size_t row = (size_t)(b * 2048 + qt * 128 + w * 32 + i * 16 + quad * 4 + r);
#pragma unroll
      for (int n = 0; n < 4; ++n)
        Hout[row * 1024 + h * 64 + n * 16 + m16] = f2bf(o[i][n][r] * inv);
    }
}

// ------------------------------ orchestration -------------------------------

extern "C" void kernel_launch(void* const* d_in, const int* in_sizes, int n_in,
                              void* d_out, int out_size, void* d_ws, size_t ws_size,
                              hipStream_t stream) {
  (void)in_sizes; (void)n_in; (void)out_size; (void)ws_size;
  const float* x   = (const float*)d_in[0];
  const int*   pos = (const int*)  d_in[1];
  const float* q_w = (const float*)d_in[2];
  const float* k_w = (const float*)d_in[3];
  const float* v_w = (const float*)d_in[4];
  const float* o_w = (const float*)d_in[5];
  const float* g1  = (const float*)d_in[6];
  const float* g2  = (const float*)d_in[7];
  const float* w1  = (const float*)d_in[8];
  const float* w2  = (const float*)d_in[9];
  const float* w3  = (const float*)d_in[10];

  char* ws = (char*)d_ws;
  uint16_t* wqk_hi = (uint16_t*)(ws + 0);
  uint16_t* wqk_lo = (uint16_t*)(ws + 4194304);
  uint16_t* wv     = (uint16_t*)(ws + 8388608);
  uint16_t* wo     = (uint16_t*)(ws + 10485760);
  uint16_t* w1b    = (uint16_t*)(ws + 12582912);
  uint16_t* w3b    = (uint16_t*)(ws + 20971520);
  uint16_t* w2b    = (uint16_t*)(ws + 29360128);
  uint16_t* xn_hi  = (uint16_t*)(ws + 37748736);
  uint16_t* xn_lo  = (uint16_t*)(ws + 54525952);
  uint16_t* vt     = (uint16_t*)(ws + 88080384);   // [1024][8192] bf16 = 16.7 MB
  uint16_t* qk_hi  = (uint16_t*)(ws + 104857600);
  uint16_t* qk_lo  = (uint16_t*)(ws + 138412032);
  uint16_t* hbuf   = (uint16_t*)(ws + 171966464);
  float*    ores   = (float*)   (ws + 188743680);
  uint16_t* on2    = (uint16_t*)(ws + 222298112);
  // overlays (regions dead by the time these are written):
  uint16_t* abuf   = (uint16_t*)(ws + 104857600);  // over qk_hi+qk_lo (67.1 MB)
  uint16_t* gbuf   = (uint16_t*)(ws + 37748736);   // over xn_hi..vt   (67.1 MB)
  float2*   cstab  = (float2*)  (ws + 222298112);  // over on2: table consumed
  // in gemm_split256_k (early); on2 written much later by rmsnorm<false>.
  // total ws required: 239,075,328 bytes

  cvt_split_qk_k<<<2048, 256, 0, stream>>>(q_w, k_w, wqk_hi, wqk_lo);
  cvt_all_k<<<14592, 256, 0, stream>>>(v_w, o_w, w1, w3, w2, pos,
                                       wv, wo, w1b, w3b, w2b, cstab);

  rmsnorm_k<true><<<8192, 256, 0, stream>>>(x, g1, xn_hi, xn_lo);

  // QKV split GEMM with fused table-driven RoPE epilogue
  gemm_split256_k<<<dim3(8, 32), 512, 0, stream>>>(xn_hi, xn_lo, wqk_hi, wqk_lo,
                                                   qk_hi, qk_lo, cstab, 2048, 1024);
  // V^T directly: Vt[1024][8192] = Wv @ Xn^T (operand swap = free transpose)
  gemm_bt_k<0><<<dim3(64, 8), 256, 0, stream>>>(wv, xn_hi, (void*)vt, nullptr, 8192, 1024);

  flash_k<<<dim3(16, 64), 256, 0, stream>>>(qk_hi, qk_lo, vt, hbuf);

  gemm_bt_k<1><<<dim3(8, 64), 256, 0, stream>>>(hbuf, wo, (void*)ores, x, 1024, 1024);

  rmsnorm_k<false><<<8192, 256, 0, stream>>>(ores, g2, on2, nullptr);

  gemm256_k<0><<<dim3(16, 32), 512, 0, stream>>>(on2, w1b, abuf, nullptr, 4096, 1024);
  gemm256_k<2><<<dim3(16, 32), 512, 0, stream>>>(on2, w3b, gbuf, abuf, 4096, 1024);

  gemm_bt_k<1><<<dim3(8, 64), 256, 0, stream>>>(gbuf, w2b, d_out, ores, 1024, 4096);
}

// Round 12
// 751.321 us; speedup vs baseline: 1.2479x; 1.2479x over previous
//
#include <hip/hip_runtime.h>
#include <stdint.h>

// ---------------------------------------------------------------------------
// TransformerBlock: rmsnorm -> QKV -> RoPE -> causal flash attn -> +x ->
//                   rmsnorm -> swiglu FFN -> +O
// bf16 MFMA everywhere; Q/K path uses hi/lo bf16 split (3-pass MFMA).
// R18: flash_k grid (16,64)->(64,16): qt on the SLOW axis (bh = bx, qt =
//      15 - by). R17 put qt on the fast axis, so long (qt=15) blocks got
//      linear IDs 0,16,...,1008 - dispatched throughout INCLUDING LAST ->
//      ~140us near-empty tail (occupancy 12.5%, dur 275us). Now IDs 0..63
//      are ALL long blocks (true LPT), IDs 960..1023 the 2-iter backfill.
//      Body identical to R16/R17. FALLBACK: if this doesn't beat R16's
//      154us, revert to the R16 paired (8,64) kernel.
// R16: (a) flash_k K single-buffered (K(kt+1) staged mid-iter post-QK-bar;
//      V dbuf). LDS 66->51.2KB -> 3 blocks/CU capacity. 3 barriers/iter.
//      FIFO: bar -> V(kt+1)[2] -> vmcnt(2) -> bar -> QK -> bar -> K(kt+1)[4]
//      -> softmax/PV.  (b) cvt_all_k merges 5 cvt launches + cs_tab.
// R15: flash_k denominator via MFMA-with-ones (ls2 = mfma(P, ones));
//      deleted the 16-lane shfl-sum. 183->153us, VGPR 124. Verified.
// R14: RoPE table (cs_tab [2048][32]) + table-lookup epilogue in
//      gemm_split256_k (R13's 128 sincosf/thread was a +50us regression).
// R12/R13: RoPE fused into gemm_split256_k epilogue; rope_k deleted.
//      flash_k P-write via v_cvt_pk_bf16_f32.
// R11/R10: flash_k = R8 body (VGPR pinned ~128; R9's defer-max +28 VGPR
//      halved occupancy -> reverted).
// R9: gemm_split256_k - QKV split GEMM on 256x256 4-phase schedule (neutral).
// R8: gemm256_k 256x256 4-phase for w1/w3; swiglu fused into w3 epilogue;
//     V^T via operand swap (Vt = Wv @ Xn^T).
// R7: flash_k K/V LDS dbuf + counted vmcnt prefetch, raw s_barriers,
//     wave-private P, diag-only masking, exp2 fold, setprio. (240->182us.)
// ---------------------------------------------------------------------------

typedef short bf16x8 __attribute__((ext_vector_type(8)));
typedef float f32x4  __attribute__((ext_vector_type(4)));

#define DEV static __device__ __forceinline__

DEV float bf2f(uint32_t u) { uint32_t v = u << 16; float f; __builtin_memcpy(&f, &v, 4); return f; }
DEV uint16_t f2bf(float f) {
  uint32_t u; __builtin_memcpy(&u, &f, 4);
  u = (u + 0x7fffu + ((u >> 16) & 1u)) >> 16;   // RNE
  return (uint16_t)u;
}

DEV void gl_lds16(const uint16_t* g, uint16_t* l) {
  __builtin_amdgcn_global_load_lds((const __attribute__((address_space(1))) uint32_t*)g,
                                   (__attribute__((address_space(3))) uint32_t*)l, 16, 0, 0);
}

// ------------------- merged weight conversion + RoPE table ------------------
// blocks [0,1024) v_w; [1024,2048) o_w; [2048,6144) w1; [6144,10240) w3;
// [10240,14336) w2; [14336,14592) cos/sin table [2048 pos][32 d2].

__global__ __launch_bounds__(256) void cvt_all_k(
    const float* __restrict__ v_w, const float* __restrict__ o_w,
    const float* __restrict__ w1, const float* __restrict__ w3,
    const float* __restrict__ w2, const int* __restrict__ pos,
    uint16_t* __restrict__ wv, uint16_t* __restrict__ wo,
    uint16_t* __restrict__ w1b, uint16_t* __restrict__ w3b,
    uint16_t* __restrict__ w2b, float2* __restrict__ cstab) {
  const int b = blockIdx.x;
  if (b >= 14336) {
    const int t = (b - 14336) * 256 + threadIdx.x;   // 2048*32
    const int p = t >> 5, d2 = t & 31;
    const float inv_freq = exp2f((float)d2 * -0.41524101186092029f);
    float sn, cs; sincosf((float)pos[p] * inv_freq, &sn, &cs);
    cstab[t] = make_float2(cs, sn);
    return;
  }
  const float* src; uint16_t* dst; int t;
  if (b < 1024)       { src = v_w; dst = wv;  t = b * 256 + threadIdx.x; }
  else if (b < 2048)  { src = o_w; dst = wo;  t = (b - 1024) * 256 + threadIdx.x; }
  else if (b < 6144)  { src = w1;  dst = w1b; t = (b - 2048) * 256 + threadIdx.x; }
  else if (b < 10240) { src = w3;  dst = w3b; t = (b - 6144) * 256 + threadIdx.x; }
  else                { src = w2;  dst = w2b; t = (b - 10240) * 256 + threadIdx.x; }
  const float4 v = ((const float4*)src)[t];
  ushort4 o; o.x = f2bf(v.x); o.y = f2bf(v.y); o.z = f2bf(v.z); o.w = f2bf(v.w);
  ((ushort4*)dst)[t] = o;
}

__global__ __launch_bounds__(256) void cvt_split_qk_k(const float* __restrict__ qw,
                                                      const float* __restrict__ kw,
                                                      uint16_t* __restrict__ hi,
                                                      uint16_t* __restrict__ lo) {
  const int t = blockIdx.x * 256 + threadIdx.x;    // 2048*256 float4s
  const int row = t >> 8, c4 = t & 255;
  const float* src = (row < 1024) ? (qw + (size_t)row * 1024)
                                  : (kw + (size_t)(row - 1024) * 1024);
  const float4 v = ((const float4*)src)[c4];
  ushort4 h, l;
  h.x = f2bf(v.x); l.x = f2bf(v.x - bf2f(h.x));
  h.y = f2bf(v.y); l.y = f2bf(v.y - bf2f(h.y));
  h.z = f2bf(v.z); l.z = f2bf(v.z - bf2f(h.z));
  h.w = f2bf(v.w); l.w = f2bf(v.w - bf2f(h.w));
  ((ushort4*)hi)[t] = h; ((ushort4*)lo)[t] = l;
}

// -------------------------------- rmsnorm ----------------------------------

template <bool SPLIT>
__global__ __launch_bounds__(256) void rmsnorm_k(const float* __restrict__ xin,
                                                 const float* __restrict__ g,
                                                 uint16_t* __restrict__ hi,
                                                 uint16_t* __restrict__ lo) {
  const int row = blockIdx.x, t = threadIdx.x;
  const float4 v = ((const float4*)(xin + (size_t)row * 1024))[t];
  float ss = v.x * v.x + v.y * v.y + v.z * v.z + v.w * v.w;
#pragma unroll
  for (int m = 1; m < 64; m <<= 1) ss += __shfl_xor(ss, m);
  __shared__ float red[4];
  if ((t & 63) == 0) red[t >> 6] = ss;
  __syncthreads();
  const float rinv = rsqrtf((red[0] + red[1] + red[2] + red[3]) * (1.0f / 1024.0f) + 1e-5f);
  const float4 gv = ((const float4*)g)[t];
  float y[4] = { v.x * rinv * gv.x, v.y * rinv * gv.y, v.z * rinv * gv.z, v.w * rinv * gv.w };
  ushort4 h; h.x = f2bf(y[0]); h.y = f2bf(y[1]); h.z = f2bf(y[2]); h.w = f2bf(y[3]);
  ((ushort4*)(hi + (size_t)row * 1024))[t] = h;
  if constexpr (SPLIT) {
    ushort4 l;
    l.x = f2bf(y[0] - bf2f(h.x)); l.y = f2bf(y[1] - bf2f(h.y));
    l.z = f2bf(y[2] - bf2f(h.z)); l.w = f2bf(y[3] - bf2f(h.w));
    ((ushort4*)(lo + (size_t)row * 1024))[t] = l;
  }
}

// ------------------------ GEMM  C[M,N] = A[M,K] @ B[N,K]^T ------------------
// 128x128 tile, BK=64, 4 waves (2x2), 16x16x32 bf16 MFMA.
// LDS tiles XOR-swizzled: slot [r][g] holds global colgrp g^(r&7).

template <int OUT>   // 0: bf16 out; 1: f32 out + residual add
__global__ __launch_bounds__(256) void gemm_bt_k(const uint16_t* __restrict__ A,
                                                 const uint16_t* __restrict__ B,
                                                 void* __restrict__ C,
                                                 const float* __restrict__ resid,
                                                 int N, int K) {
  __shared__ __align__(16) uint16_t As[128 * 64];
  __shared__ __align__(16) uint16_t Bs[128 * 64];
  const int t = threadIdx.x, w = t >> 6, lane = t & 63, m16 = lane & 15, quad = lane >> 4;
  const int wm = (w >> 1) * 64, wn = (w & 1) * 64;
  const int mBase = blockIdx.y * 128, nBase = blockIdx.x * 128;
  f32x4 acc[4][4];
  const f32x4 vz = {0.f, 0.f, 0.f, 0.f};
#pragma unroll
  for (int i = 0; i < 4; ++i)
#pragma unroll
    for (int j = 0; j < 4; ++j) acc[i][j] = vz;
  const int r_ = t >> 3, g_ = t & 7, sg = g_ ^ (r_ & 7);   // (it*32) % 8 == 0
  const uint16_t* ag = A + (size_t)(mBase + r_) * K + sg * 8;
  const uint16_t* bg = B + (size_t)(nBase + r_) * K + sg * 8;
  for (int k0 = 0; k0 < K; k0 += 64) {
#pragma unroll
    for (int it = 0; it < 4; ++it) {
      gl_lds16(ag + (size_t)(it * 32) * K + k0, As + it * 2048 + t * 8);
      gl_lds16(bg + (size_t)(it * 32) * K + k0, Bs + it * 2048 + t * 8);
    }
    __syncthreads();
#pragma unroll
    for (int ks = 0; ks < 2; ++ks) {
      bf16x8 af[4], bf4[4];
      const int cg = ks * 4 + quad;
#pragma unroll
      for (int i = 0; i < 4; ++i) {
        const int rA = wm + i * 16 + m16;
        af[i] = *(const bf16x8*)(As + rA * 64 + ((cg ^ (rA & 7)) * 8));
        const int rB = wn + i * 16 + m16;
        bf4[i] = *(const bf16x8*)(Bs + rB * 64 + ((cg ^ (rB & 7)) * 8));
      }
#pragma unroll
      for (int i = 0; i < 4; ++i)
#pragma unroll
        for (int j = 0; j < 4; ++j)
          acc[i][j] = __builtin_amdgcn_mfma_f32_16x16x32_bf16(af[i], bf4[j], acc[i][j], 0, 0, 0);
    }
    __syncthreads();
  }
#pragma unroll
  for (int i = 0; i < 4; ++i) {
    const int row0 = mBase + wm + i * 16 + quad * 4;
#pragma unroll
    for (int j = 0; j < 4; ++j) {
      const int col = nBase + wn + j * 16 + m16;
#pragma unroll
      for (int r = 0; r < 4; ++r) {
        const size_t idx = (size_t)(row0 + r) * N + col;
        const float v = acc[i][j][r];
        if constexpr (OUT == 1) ((float*)C)[idx] = v + resid[idx];
        else                    ((uint16_t*)C)[idx] = f2bf(v);
      }
    }
  }
}

// -------------- 256x256 8-phase GEMM  C[M,N] = A[M,K] @ B[N,K]^T ------------
// BK=64, 512 thr = 8 waves (2M x 4N), per-wave 128x64 out = acc[8][4].
// LDS: A/B double-buffered 256x64 each = 128 KiB. Stage 2 tiles ahead,
// 1 half-tile (2 gl_lds) per phase; vmcnt(6) once per K-tile (phase 0).

template <int OUT>   // 0: bf16 store; 2: bf16 store of silu(aux)*acc (fused swiglu)
__global__ __launch_bounds__(512, 2) void gemm256_k(const uint16_t* __restrict__ A,
                                                    const uint16_t* __restrict__ B,
                                                    uint16_t* __restrict__ C,
                                                    const uint16_t* __restrict__ aux,
                                                    int N, int K) {
  __shared__ __align__(16) uint16_t As[2][256 * 64];
  __shared__ __align__(16) uint16_t Bs[2][256 * 64];
  const int t = threadIdx.x, w = t >> 6, lane = t & 63, m16 = lane & 15, quad = lane >> 4;
  const int wm = (w >> 2) * 128, wn = (w & 3) * 64;
  const int mBase = blockIdx.y * 256, nBase = blockIdx.x * 256;
  const int NT = K >> 6;

  f32x4 acc[8][4];
  const f32x4 vz = {0.f, 0.f, 0.f, 0.f};
#pragma unroll
  for (int i = 0; i < 8; ++i)
#pragma unroll
    for (int j = 0; j < 4; ++j) acc[i][j] = vz;

  const int r_ = t >> 3, g_ = t & 7, sg = g_ ^ (r_ & 7);   // 64-row chunks keep (row&7)
  const uint16_t* ag = A + (size_t)(mBase + r_) * K + sg * 8;
  const uint16_t* bg = B + (size_t)(nBase + r_) * K + sg * 8;

#define STG_A(kt, h)                                                         \
  if ((kt) < NT) {                                                           \
    uint16_t* d0 = &As[(kt) & 1][(h) * 8192 + t * 8];                        \
    const uint16_t* s0 = ag + (size_t)((h) * 128) * K + (kt) * 64;           \
    gl_lds16(s0, d0);                                                        \
    gl_lds16(s0 + (size_t)64 * K, d0 + 4096);                                \
  }
#define STG_B(kt, h)                                                         \
  if ((kt) < NT) {                                                           \
    uint16_t* d0 = &Bs[(kt) & 1][(h) * 8192 + t * 8];                        \
    const uint16_t* s0 = bg + (size_t)((h) * 128) * K + (kt) * 64;           \
    gl_lds16(s0, d0);                                                        \
    gl_lds16(s0 + (size_t)64 * K, d0 + 4096);                                \
  }

  // prologue: tile0 fully + tile1's Bh0/Ah0 (oldest-first for vmcnt math)
  STG_B(0, 0); STG_B(0, 1); STG_A(0, 0); STG_A(0, 1);
  STG_B(1, 0); STG_A(1, 0);

  for (int T = 0; T < NT; ++T) {
    const int c = T & 1;
    const uint16_t* Ac = As[c];
    const uint16_t* Bc = Bs[c];
    bf16x8 af[4][2], b0[2][2], b1[2][2];

    // ---------------- ph0: quadrant (mq0, nq0) ----------------
    STG_B(T + 1, 1);
    if (T == NT - 1) { asm volatile("s_waitcnt vmcnt(0)" ::: "memory"); }
    else             { asm volatile("s_waitcnt vmcnt(6)" ::: "memory"); }
    __builtin_amdgcn_s_barrier();
    __builtin_amdgcn_sched_barrier(0);
#pragma unroll
    for (int i = 0; i < 4; ++i) {
      const int rA = wm + i * 16 + m16;
#pragma unroll
      for (int ks = 0; ks < 2; ++ks)
        af[i][ks] = *(const bf16x8*)(Ac + rA * 64 + (((ks * 4 + quad) ^ (rA & 7)) * 8));
    }
#pragma unroll
    for (int j = 0; j < 2; ++j) {
      const int rB = wn + j * 16 + m16;
#pragma unroll
      for (int ks = 0; ks < 2; ++ks)
        b0[j][ks] = *(const bf16x8*)(Bc + rB * 64 + (((ks * 4 + quad) ^ (rB & 7)) * 8));
    }
    __builtin_amdgcn_s_setprio(1);
#pragma unroll
    for (int ks = 0; ks < 2; ++ks)
#pragma unroll
      for (int i = 0; i < 4; ++i)
#pragma unroll
        for (int j = 0; j < 2; ++j)
          acc[i][j] = __builtin_amdgcn_mfma_f32_16x16x32_bf16(af[i][ks], b0[j][ks], acc[i][j], 0, 0, 0);
    __builtin_amdgcn_s_setprio(0);
    __builtin_amdgcn_s_barrier();

    // ---------------- ph1: (mq0, nq1) ----------------
    STG_A(T + 1, 1);
#pragma unroll
    for (int j = 0; j < 2; ++j) {
      const int rB = wn + (2 + j) * 16 + m16;
#pragma unroll
      for (int ks = 0; ks < 2; ++ks)
        b1[j][ks] = *(const bf16x8*)(Bc + rB * 64 + (((ks * 4 + quad) ^ (rB & 7)) * 8));
    }
    __builtin_amdgcn_s_setprio(1);
#pragma unroll
    for (int ks = 0; ks < 2; ++ks)
#pragma unroll
      for (int i = 0; i < 4; ++i)
#pragma unroll
        for (int j = 0; j < 2; ++j)
          acc[i][2 + j] = __builtin_amdgcn_mfma_f32_16x16x32_bf16(af[i][ks], b1[j][ks], acc[i][2 + j], 0, 0, 0);
    __builtin_amdgcn_s_setprio(0);
    __builtin_amdgcn_s_barrier();

    // ---------------- ph2: (mq1, nq0) ----------------
    STG_B(T + 2, 0);
#pragma unroll
    for (int i = 0; i < 4; ++i) {
      const int rA = wm + 64 + i * 16 + m16;
#pragma unroll
      for (int ks = 0; ks < 2; ++ks)
        af[i][ks] = *(const bf16x8*)(Ac + rA * 64 + (((ks * 4 + quad) ^ (rA & 7)) * 8));
    }
    __builtin_amdgcn_s_setprio(1);
#pragma unroll
    for (int ks = 0; ks < 2; ++ks)
#pragma unroll
      for (int i = 0; i < 4; ++i)
#pragma unroll
        for (int j = 0; j < 2; ++j)
          acc[4 + i][j] = __builtin_amdgcn_mfma_f32_16x16x32_bf16(af[i][ks], b0[j][ks], acc[4 + i][j], 0, 0, 0);
    __builtin_amdgcn_s_setprio(0);
    __builtin_amdgcn_s_barrier();

    // ---------------- ph3: (mq1, nq1) ----------------
    STG_A(T + 2, 0);
    __builtin_amdgcn_s_setprio(1);
#pragma unroll
    for (int ks = 0; ks < 2; ++ks)
#pragma unroll
      for (int i = 0; i < 4; ++i)
#pragma unroll
        for (int j = 0; j < 2; ++j)
          acc[4 + i][2 + j] = __builtin_amdgcn_mfma_f32_16x16x32_bf16(af[i][ks], b1[j][ks], acc[4 + i][2 + j], 0, 0, 0);
    __builtin_amdgcn_s_setprio(0);
    __builtin_amdgcn_s_barrier();
  }
#undef STG_A
#undef STG_B

#pragma unroll
  for (int i = 0; i < 8; ++i) {
    const int row0 = mBase + wm + i * 16 + quad * 4;
#pragma unroll
    for (int j = 0; j < 4; ++j) {
      const int col = nBase + wn + j * 16 + m16;
#pragma unroll
      for (int r = 0; r < 4; ++r) {
        const size_t idx = (size_t)(row0 + r) * N + col;
        const float v = acc[i][j][r];
        if constexpr (OUT == 2) {
          const float a = bf2f(aux[idx]);
          const float sw = a / (1.f + __expf(-a));
          C[idx] = f2bf(sw * v);
        } else {
          C[idx] = f2bf(v);
        }
      }
    }
  }
}

// -------- 256x256 4-phase split-precision GEMM (Q/K projection), BK=32 -----
// acc += Ahi*Bhi + Ahi*Blo + Alo*Bhi  (drops lo*lo: ~2^-18 relative)
// 512 thr = 8 waves (2M x 4N), per-wave 128x64 = acc[8][4]; 24 MFMA/phase.
// LDS: Ah/Al/Bh/Bl dbuf 256x32 each = 128 KiB.
// Stage stream: ph0->AH(T+1), ph1->AL(T+1), ph2->BH(T+2), ph3->BL(T+2).
// vmcnt(6) at ph0: FIFO = [B(T)4, AH(T)2, AL(T)2, B(T+1)4, AH(T+1)2] ->
// keep newest 6, drain tile T's 8. Prologue order B(0),A(0),B(1) matches.
// R12: RoPE fused in the epilogue - adjacent (even,odd) columns live in
// adjacent lanes, one __shfl_xor(v,1) pairs them; rotate fp32, then split.
// R14: cos/sin from precomputed table (cached 8B loads) - no sincosf here.

__global__ __launch_bounds__(512, 2) void gemm_split256_k(
    const uint16_t* __restrict__ Ahi, const uint16_t* __restrict__ Alo,
    const uint16_t* __restrict__ Bhi, const uint16_t* __restrict__ Blo,
    uint16_t* __restrict__ Chi, uint16_t* __restrict__ Clo,
    const float2* __restrict__ cstab, int N, int K) {
  __shared__ __align__(16) uint16_t Ah[2][256 * 32];
  __shared__ __align__(16) uint16_t Al[2][256 * 32];
  __shared__ __align__(16) uint16_t Bh[2][256 * 32];
  __shared__ __align__(16) uint16_t Bl[2][256 * 32];
  const int t = threadIdx.x, w = t >> 6, lane = t & 63, m16 = lane & 15, quad = lane >> 4;
  const int wm = (w >> 2) * 128, wn = (w & 3) * 64;
  const int mBase = blockIdx.y * 256, nBase = blockIdx.x * 256;
  const int NT = K >> 5;

  f32x4 acc[8][4];
  const f32x4 vz = {0.f, 0.f, 0.f, 0.f};
#pragma unroll
  for (int i = 0; i < 8; ++i)
#pragma unroll
    for (int j = 0; j < 4; ++j) acc[i][j] = vz;

  const int r_ = t >> 2, g_ = t & 3, sg = g_ ^ (r_ & 3);   // rows stack by 128: (r&3) kept
  const uint16_t* agh = Ahi + (size_t)(mBase + r_) * K + sg * 8;
  const uint16_t* agl = Alo + (size_t)(mBase + r_) * K + sg * 8;
  const uint16_t* bgh = Bhi + (size_t)(nBase + r_) * K + sg * 8;
  const uint16_t* bgl = Blo + (size_t)(nBase + r_) * K + sg * 8;

  // one operand, one K-tile = 256x32 = 16KB = 2 issues (rows 0-127, 128-255)
#define STG4(OP, base, kt)                                                   \
  if ((kt) < NT) {                                                           \
    uint16_t* d = &OP[(kt) & 1][t * 8];                                      \
    const uint16_t* s = (base) + (size_t)(kt) * 32;                          \
    gl_lds16(s, d);                                                          \
    gl_lds16(s + (size_t)128 * K, d + 4096);                                 \
  }

  // prologue (FIFO order = steady-state expectation for T=0)
  STG4(Bh, bgh, 0); STG4(Bl, bgl, 0);
  STG4(Ah, agh, 0); STG4(Al, agl, 0);
  STG4(Bh, bgh, 1); STG4(Bl, bgl, 1);

  for (int T = 0; T < NT; ++T) {
    const int c = T & 1;
    bf16x8 a_h[4], a_l[4], b0h[2], b0l[2], b1h[2], b1l[2];

    // ---------------- ph0: (mq0, nq0) ----------------
    STG4(Ah, agh, T + 1);
    if (T == NT - 1) { asm volatile("s_waitcnt vmcnt(0)" ::: "memory"); }
    else             { asm volatile("s_waitcnt vmcnt(6)" ::: "memory"); }
    __builtin_amdgcn_s_barrier();
    __builtin_amdgcn_sched_barrier(0);
#pragma unroll
    for (int i = 0; i < 4; ++i) {
      const int rA = wm + i * 16 + m16;
      const int offA = rA * 32 + ((quad ^ (rA & 3)) * 8);
      a_h[i] = *(const bf16x8*)(&Ah[c][offA]);
      a_l[i] = *(const bf16x8*)(&Al[c][offA]);
    }
#pragma unroll
    for (int j = 0; j < 2; ++j) {
      const int rB = wn + j * 16 + m16;
      const int offB = rB * 32 + ((quad ^ (rB & 3)) * 8);
      b0h[j] = *(const bf16x8*)(&Bh[c][offB]);
      b0l[j] = *(const bf16x8*)(&Bl[c][offB]);
    }
    __builtin_amdgcn_s_setprio(1);
#pragma unroll
    for (int i = 0; i < 4; ++i)
#pragma unroll
      for (int j = 0; j < 2; ++j) {
        acc[i][j] = __builtin_amdgcn_mfma_f32_16x16x32_bf16(a_h[i], b0h[j], acc[i][j], 0, 0, 0);
        acc[i][j] = __builtin_amdgcn_mfma_f32_16x16x32_bf16(a_h[i], b0l[j], acc[i][j], 0, 0, 0);
        acc[i][j] = __builtin_amdgcn_mfma_f32_16x16x32_bf16(a_l[i], b0h[j], acc[i][j], 0, 0, 0);
      }
    __builtin_amdgcn_s_setprio(0);
    __builtin_amdgcn_s_barrier();

    // ---------------- ph1: (mq0, nq1) ----------------
    STG4(Al, agl, T + 1);
#pragma unroll
    for (int j = 0; j < 2; ++j) {
      const int rB = wn + (2 + j) * 16 + m16;
      const int offB = rB * 32 + ((quad ^ (rB & 3)) * 8);
      b1h[j] = *(const bf16x8*)(&Bh[c][offB]);
      b1l[j] = *(const bf16x8*)(&Bl[c][offB]);
    }
    __builtin_amdgcn_s_setprio(1);
#pragma unroll
    for (int i = 0; i < 4; ++i)
#pragma unroll
      for (int j = 0; j < 2; ++j) {
        acc[i][2 + j] = __builtin_amdgcn_mfma_f32_16x16x32_bf16(a_h[i], b1h[j], acc[i][2 + j], 0, 0, 0);
        acc[i][2 + j] = __builtin_amdgcn_mfma_f32_16x16x32_bf16(a_h[i], b1l[j], acc[i][2 + j], 0, 0, 0);
        acc[i][2 + j] = __builtin_amdgcn_mfma_f32_16x16x32_bf16(a_l[i], b1h[j], acc[i][2 + j], 0, 0, 0);
      }
    __builtin_amdgcn_s_setprio(0);
    __builtin_amdgcn_s_barrier();

    // ---------------- ph2: (mq1, nq0) ----------------
    STG4(Bh, bgh, T + 2);
#pragma unroll
    for (int i = 0; i < 4; ++i) {
      const int rA = wm + 64 + i * 16 + m16;
      const int offA = rA * 32 + ((quad ^ (rA & 3)) * 8);
      a_h[i] = *(const bf16x8*)(&Ah[c][offA]);
      a_l[i] = *(const bf16x8*)(&Al[c][offA]);
    }
    __builtin_amdgcn_s_setprio(1);
#pragma unroll
    for (int i = 0; i < 4; ++i)
#pragma unroll
      for (int j = 0; j < 2; ++j) {
        acc[4 + i][j] = __builtin_amdgcn_mfma_f32_16x16x32_bf16(a_h[i], b0h[j], acc[4 + i][j], 0, 0, 0);
        acc[4 + i][j] = __builtin_amdgcn_mfma_f32_16x16x32_bf16(a_h[i], b0l[j], acc[4 + i][j], 0, 0, 0);
        acc[4 + i][j] = __builtin_amdgcn_mfma_f32_16x16x32_bf16(a_l[i], b0h[j], acc[4 + i][j], 0, 0, 0);
      }
    __builtin_amdgcn_s_setprio(0);
    __builtin_amdgcn_s_barrier();

    // ---------------- ph3: (mq1, nq1) ----------------
    STG4(Bl, bgl, T + 2);
    __builtin_amdgcn_s_setprio(1);
#pragma unroll
    for (int i = 0; i < 4; ++i)
#pragma unroll
      for (int j = 0; j < 2; ++j) {
        acc[4 + i][2 + j] = __builtin_amdgcn_mfma_f32_16x16x32_bf16(a_h[i], b1h[j], acc[4 + i][2 + j], 0, 0, 0);
        acc[4 + i][2 + j] = __builtin_amdgcn_mfma_f32_16x16x32_bf16(a_h[i], b1l[j], acc[4 + i][2 + j], 0, 0, 0);
        acc[4 + i][2 + j] = __builtin_amdgcn_mfma_f32_16x16x32_bf16(a_l[i], b1h[j], acc[4 + i][2 + j], 0, 0, 0);
      }
    __builtin_amdgcn_s_setprio(0);
    __builtin_amdgcn_s_barrier();
  }
#undef STG4

  // ---- epilogue: fused RoPE (table-driven, fp32) + hi/lo split store ----
  int d2v[4];
#pragma unroll
  for (int j = 0; j < 4; ++j)
    d2v[j] = ((nBase + wn + j * 16 + m16) & 63) >> 1;
  const bool oddc = (m16 & 1) != 0;
#pragma unroll
  for (int i = 0; i < 8; ++i) {
    const int row0 = mBase + wm + i * 16 + quad * 4;
#pragma unroll
    for (int r = 0; r < 4; ++r) {
      const int row = row0 + r;
      const float2* crow = cstab + (size_t)(row & 2047) * 32;
      const size_t rb = (size_t)row * N;
#pragma unroll
      for (int j = 0; j < 4; ++j) {
        const float v = acc[i][j][r];
        const float pv = __shfl_xor(v, 1);      // partner column's value
        const float xe = oddc ? pv : v;
        const float xo = oddc ? v : pv;
        const float2 cs = crow[d2v[j]];         // (cos, sin)
        const float vr = oddc ? (xe * cs.y + xo * cs.x) : (xe * cs.x - xo * cs.y);
        const size_t idx = rb + (nBase + wn + j * 16 + m16);
        const uint16_t hh = f2bf(vr);
        Chi[idx] = hh;
        Clo[idx] = f2bf(vr - bf2f(hh));
      }
    }
  }
}

// ----------------------- causal flash attention -----------------------------
// R18: grid (64,16): bh = blockIdx.x (FAST axis), qt = 15 - blockIdx.y
// (SLOW axis). Linear IDs 0..63 = all 64 longest (qt=15) blocks -> true LPT;
// IDs 960..1023 = the 2-iter blocks (backfill tail).
// R16 schedule (K single-buffered, V double-buffered; 3 barriers/iter):
//   prologue: stage K(0)[4 DMA] then V(0)[2 DMA] into Vs[0].
//   iter kt: bar(guard: Vs[nxt] free) -> issue V(kt+1)->Vs[nxt] ->
//            vmcnt(2) [K(kt)+V(kt) done; V(kt+1) in flight] -> bar ->
//            QK MFMA on K LDS -> bar(K reads done) -> issue K(kt+1) ->
//            softmax -> P write -> PV on Vs[cur].
// LDS 51.2KB (Kh 8K + Kl 8K + Vs 16K + P 18.4K) -> 3 blocks/CU.
// R15: denominator via MFMA-with-ones. R12: cvt_pk P-write. VGPR ~116-124 -
// DO NOT grow registers (R9 lesson).
// Vt layout [1024 d-rows][8192 tokens] (stride 8192, col b*2048+s).

__global__ __launch_bounds__(256) void flash_k(const uint16_t* __restrict__ Qh,
                                               const uint16_t* __restrict__ Ql,
                                               const uint16_t* __restrict__ Vt,
                                               uint16_t* __restrict__ Hout) {
  __shared__ __align__(16) uint16_t Kh[64 * 64];
  __shared__ __align__(16) uint16_t Kl[64 * 64];
  __shared__ __align__(16) uint16_t Vs[2][64 * 64];
  __shared__ __align__(16) uint16_t P[4][32 * 72];

  const int bh = blockIdx.x, b = bh >> 4, h = bh & 15;
  const int t = threadIdx.x, w = t >> 6, lane = t & 63, m16 = lane & 15, quad = lane >> 4;

  const int r_ = t >> 3, g_ = t & 7, sgx = g_ ^ (r_ & 7);
  const uint16_t* khg = Qh + (size_t)(b * 2048 + r_) * 2048 + 1024 + h * 64 + sgx * 8;
  const uint16_t* klg = Ql + (size_t)(b * 2048 + r_) * 2048 + 1024 + h * 64 + sgx * 8;
  const uint16_t* vtg = Vt + (size_t)(h * 64 + r_) * 8192 + (size_t)b * 2048 + sgx * 8;

  const float nscl = 0.18033688011112042f;   // log2(e)/8: fold 1/sqrt(64) + ln->log2
  bf16x8 onef;
#pragma unroll
  for (int e = 0; e < 8; ++e) onef[e] = (short)0x3F80;   // bf16 1.0

  // longest-job-first on the SLOW axis: by=0 -> qt=15 (32 KV-iters).
  const int qt = 15 - (int)blockIdx.y;

  bf16x8 qh[2][2], ql[2][2];
#pragma unroll
  for (int i = 0; i < 2; ++i) {
    const int row = b * 2048 + qt * 128 + w * 32 + i * 16 + m16;
#pragma unroll
    for (int ks = 0; ks < 2; ++ks) {
      const size_t offq = (size_t)row * 2048 + h * 64 + ks * 32 + quad * 8;
      qh[i][ks] = *(const bf16x8*)(Qh + offq);
      ql[i][ks] = *(const bf16x8*)(Ql + offq);
    }
  }
  // Pin Q fragments: forces the compiler's vmcnt drain HERE, so inside the
  // loop the outstanding-VMEM count is exactly our DMA loads.
#pragma unroll
  for (int i = 0; i < 2; ++i)
#pragma unroll
    for (int ks = 0; ks < 2; ++ks)
      asm volatile("" : "+v"(qh[i][ks]), "+v"(ql[i][ks]));

  const int ktEnd = 2 * qt + 2;

  // prologue: K(0) [4 DMA] then V(0) [2 DMA] (FIFO order for vmcnt math)
#pragma unroll
  for (int it = 0; it < 2; ++it) {
    gl_lds16(khg + (size_t)(it * 32) * 2048, &Kh[it * 2048 + t * 8]);
    gl_lds16(klg + (size_t)(it * 32) * 2048, &Kl[it * 2048 + t * 8]);
  }
#pragma unroll
  for (int it = 0; it < 2; ++it)
    gl_lds16(vtg + (size_t)(it * 32) * 8192, &Vs[0][it * 2048 + t * 8]);

  float mr[2][4];
  f32x4 o[2][4], ls2[2];
  const f32x4 vz = {0.f, 0.f, 0.f, 0.f};
#pragma unroll
  for (int i = 0; i < 2; ++i)
#pragma unroll
    for (int r = 0; r < 4; ++r) mr[i][r] = -1e30f;
  ls2[0] = vz; ls2[1] = vz;
#pragma unroll
  for (int i = 0; i < 2; ++i)
#pragma unroll
    for (int n = 0; n < 4; ++n) o[i][n] = vz;

  for (int kt = 0; kt < ktEnd; ++kt) {
    const int cur = kt & 1, nxt = cur ^ 1;
    // bar 1 (guard): all waves finished PV(kt-1) reads of Vs[nxt].
    __builtin_amdgcn_s_barrier();
    __builtin_amdgcn_sched_barrier(0);
    if (kt + 1 < ktEnd) {
#pragma unroll
      for (int it = 0; it < 2; ++it)
        gl_lds16(vtg + (size_t)(it * 32) * 8192 + (kt + 1) * 64,
                 &Vs[nxt][it * 2048 + t * 8]);
      // K(kt)[4] + V(kt)[2] must be done; keep V(kt+1)[2] in flight.
      asm volatile("s_waitcnt vmcnt(2)" ::: "memory");
    } else {
      asm volatile("s_waitcnt vmcnt(0)" ::: "memory");
    }
    // bar 2: K(kt)/V(kt) LDS data visible to all waves.
    __builtin_amdgcn_s_barrier();
    __builtin_amdgcn_sched_barrier(0);

    // ---- QK^T (3-pass hi/lo) on the single K buffer ----
    f32x4 sc[2][4];
#pragma unroll
    for (int i = 0; i < 2; ++i)
#pragma unroll
      for (int j = 0; j < 4; ++j) sc[i][j] = vz;
#pragma unroll
    for (int ks = 0; ks < 2; ++ks) {
      bf16x8 kfh[4], kfl[4];
      const int cg = ks * 4 + quad;
#pragma unroll
      for (int j = 0; j < 4; ++j) {
        const int rK = j * 16 + m16;
        const int offk = rK * 64 + ((cg ^ (rK & 7)) * 8);
        kfh[j] = *(const bf16x8*)(&Kh[offk]);
        kfl[j] = *(const bf16x8*)(&Kl[offk]);
      }
      __builtin_amdgcn_s_setprio(1);
#pragma unroll
      for (int i = 0; i < 2; ++i)
#pragma unroll
        for (int j = 0; j < 4; ++j) {
          sc[i][j] = __builtin_amdgcn_mfma_f32_16x16x32_bf16(qh[i][ks], kfh[j], sc[i][j], 0, 0, 0);
          sc[i][j] = __builtin_amdgcn_mfma_f32_16x16x32_bf16(qh[i][ks], kfl[j], sc[i][j], 0, 0, 0);
          sc[i][j] = __builtin_amdgcn_mfma_f32_16x16x32_bf16(ql[i][ks], kfh[j], sc[i][j], 0, 0, 0);
        }
      __builtin_amdgcn_s_setprio(0);
    }

    // bar 3: all waves' QK LDS reads complete -> K buffer free for kt+1.
    __builtin_amdgcn_s_barrier();
    __builtin_amdgcn_sched_barrier(0);
    if (kt + 1 < ktEnd) {
#pragma unroll
      for (int it = 0; it < 2; ++it) {
        gl_lds16(khg + (size_t)((kt + 1) * 64 + it * 32) * 2048, &Kh[it * 2048 + t * 8]);
        gl_lds16(klg + (size_t)((kt + 1) * 64 + it * 32) * 2048, &Kl[it * 2048 + t * 8]);
      }
    }

    // ---- online softmax, raw-score domain; row-sum comes from the
    //      MFMA-with-ones in the PV phase (R15), not a shfl reduce ----
#pragma unroll
    for (int i = 0; i < 2; ++i) {
      const bool needMask = (kt * 64 + 63) > (qt * 128 + w * 32 + i * 16);
#pragma unroll
      for (int r = 0; r < 4; ++r) {
        float mx = -1e30f;
        if (needMask) {
          const int qg = qt * 128 + w * 32 + i * 16 + quad * 4 + r;
#pragma unroll
          for (int j = 0; j < 4; ++j) {
            float v = sc[i][j][r];
            const int kg = kt * 64 + j * 16 + m16;
            if (kg > qg) v = -1e30f;
            sc[i][j][r] = v;
            mx = fmaxf(mx, v);
          }
        } else {
#pragma unroll
          for (int j = 0; j < 4; ++j) mx = fmaxf(mx, sc[i][j][r]);
        }
#pragma unroll
        for (int m = 1; m < 16; m <<= 1) mx = fmaxf(mx, __shfl_xor(mx, m));
        const float mnew = fmaxf(mr[i][r], mx);
        const float alpha = __builtin_amdgcn_exp2f((mr[i][r] - mnew) * nscl);
        mr[i][r] = mnew;
        const float nm = mnew * nscl;
#pragma unroll
        for (int j = 0; j < 4; ++j)
          sc[i][j][r] = __builtin_amdgcn_exp2f(__builtin_fmaf(sc[i][j][r], nscl, -nm));
        ls2[i][r] *= alpha;
#pragma unroll
        for (int n = 0; n < 4; ++n) o[i][n][r] *= alpha;
      }
      // P-write: HW packed bf16 convert (RNE), then scalar u16 stores (the
      // 4 targets per j are non-adjacent rows - stores were scalar before).
#pragma unroll
      for (int j = 0; j < 4; ++j) {
        uint32_t pk01, pk23;
        asm("v_cvt_pk_bf16_f32 %0, %1, %2"
            : "=v"(pk01) : "v"(sc[i][j][0]), "v"(sc[i][j][1]));
        asm("v_cvt_pk_bf16_f32 %0, %1, %2"
            : "=v"(pk23) : "v"(sc[i][j][2]), "v"(sc[i][j][3]));
        const int pb = (i * 16 + quad * 4) * 72 + j * 16 + m16;
        P[w][pb]       = (uint16_t)pk01;
        P[w][pb + 72]  = (uint16_t)(pk01 >> 16);
        P[w][pb + 144] = (uint16_t)pk23;
        P[w][pb + 216] = (uint16_t)(pk23 >> 16);
      }
    }
    // P[w] is wave-private: intra-wave ds_write->ds_read needs only the
    // compiler-inserted lgkmcnt, no cross-wave barrier.

#pragma unroll
    for (int ks2 = 0; ks2 < 2; ++ks2) {
      bf16x8 pf[2], vf[4];
#pragma unroll
      for (int i = 0; i < 2; ++i)
        pf[i] = *(const bf16x8*)(&P[w][(i * 16 + m16) * 72 + ks2 * 32 + quad * 8]);
      const int cg = ks2 * 4 + quad;
#pragma unroll
      for (int n = 0; n < 4; ++n) {
        const int rV = n * 16 + m16;
        vf[n] = *(const bf16x8*)(&Vs[cur][rV * 64 + ((cg ^ (rV & 7)) * 8)]);
      }
      __builtin_amdgcn_s_setprio(1);
#pragma unroll
      for (int i = 0; i < 2; ++i) {
        // R15: denominator = row-sum of P via MFMA with B = ones
        ls2[i] = __builtin_amdgcn_mfma_f32_16x16x32_bf16(pf[i], onef, ls2[i], 0, 0, 0);
#pragma unroll
        for (int n = 0; n < 4; ++n)
          o[i][n] = __builtin_amdgcn_mfma_f32_16x16x32_bf16(pf[i], vf[n], o[i][n], 0, 0, 0);
      }
      __builtin_amdgcn_s_setprio(0);
    }
  }

#pragma unroll
  for (int i = 0; i < 2; ++i)
#pragma unroll
    for (int r = 0; r < 4; ++r) {
      const float inv = 1.f / ls2[i][r];
      const size_t row = (size_t)(b * 2048 + qt * 128 + w * 32 + i * 16 + quad * 4 + r);
#pragma unroll
      for (int n = 0; n < 4; ++n)
        Hout[row * 1024 + h * 64 + n * 16 + m16] = f2bf(o[i][n][r] * inv);
    }
}

// ------------------------------ orchestration -------------------------------

extern "C" void kernel_launch(void* const* d_in, const int* in_sizes, int n_in,
                              void* d_out, int out_size, void* d_ws, size_t ws_size,
                              hipStream_t stream) {
  (void)in_sizes; (void)n_in; (void)out_size; (void)ws_size;
  const float* x   = (const float*)d_in[0];
  const int*   pos = (const int*)  d_in[1];
  const float* q_w = (const float*)d_in[2];
  const float* k_w = (const float*)d_in[3];
  const float* v_w = (const float*)d_in[4];
  const float* o_w = (const float*)d_in[5];
  const float* g1  = (const float*)d_in[6];
  const float* g2  = (const float*)d_in[7];
  const float* w1  = (const float*)d_in[8];
  const float* w2  = (const float*)d_in[9];
  const float* w3  = (const float*)d_in[10];

  char* ws = (char*)d_ws;
  uint16_t* wqk_hi = (uint16_t*)(ws + 0);
  uint16_t* wqk_lo = (uint16_t*)(ws + 4194304);
  uint16_t* wv     = (uint16_t*)(ws + 8388608);
  uint16_t* wo     = (uint16_t*)(ws + 10485760);
  uint16_t* w1b    = (uint16_t*)(ws + 12582912);
  uint16_t* w3b    = (uint16_t*)(ws + 20971520);
  uint16_t* w2b    = (uint16_t*)(ws + 29360128);
  uint16_t* xn_hi  = (uint16_t*)(ws + 37748736);
  uint16_t* xn_lo  = (uint16_t*)(ws + 54525952);
  uint16_t* vt     = (uint16_t*)(ws + 88080384);   // [1024][8192] bf16 = 16.7 MB
  uint16_t* qk_hi  = (uint16_t*)(ws + 104857600);
  uint16_t* qk_lo  = (uint16_t*)(ws + 138412032);
  uint16_t* hbuf   = (uint16_t*)(ws + 171966464);
  float*    ores   = (float*)   (ws + 188743680);
  uint16_t* on2    = (uint16_t*)(ws + 222298112);
  // overlays (regions dead by the time these are written):
  uint16_t* abuf   = (uint16_t*)(ws + 104857600);  // over qk_hi+qk_lo (67.1 MB)
  uint16_t* gbuf   = (uint16_t*)(ws + 37748736);   // over xn_hi..vt   (67.1 MB)
  float2*   cstab  = (float2*)  (ws + 222298112);  // over on2: table consumed
  // in gemm_split256_k (early); on2 written much later by rmsnorm<false>.
  // total ws required: 239,075,328 bytes

  cvt_split_qk_k<<<2048, 256, 0, stream>>>(q_w, k_w, wqk_hi, wqk_lo);
  cvt_all_k<<<14592, 256, 0, stream>>>(v_w, o_w, w1, w3, w2, pos,
                                       wv, wo, w1b, w3b, w2b, cstab);

  rmsnorm_k<true><<<8192, 256, 0, stream>>>(x, g1, xn_hi, xn_lo);

  // QKV split GEMM with fused table-driven RoPE epilogue
  gemm_split256_k<<<dim3(8, 32), 512, 0, stream>>>(xn_hi, xn_lo, wqk_hi, wqk_lo,
                                                   qk_hi, qk_lo, cstab, 2048, 1024);
  // V^T directly: Vt[1024][8192] = Wv @ Xn^T (operand swap = free transpose)
  gemm_bt_k<0><<<dim3(64, 8), 256, 0, stream>>>(wv, xn_hi, (void*)vt, nullptr, 8192, 1024);

  flash_k<<<dim3(64, 16), 256, 0, stream>>>(qk_hi, qk_lo, vt, hbuf);

  gemm_bt_k<1><<<dim3(8, 64), 256, 0, stream>>>(hbuf, wo, (void*)ores, x, 1024, 1024);

  rmsnorm_k<false><<<8192, 256, 0, stream>>>(ores, g2, on2, nullptr);

  gemm256_k<0><<<dim3(16, 32), 512, 0, stream>>>(on2, w1b, abuf, nullptr, 4096, 1024);
  gemm256_k<2><<<dim3(16, 32), 512, 0, stream>>>(on2, w3b, gbuf, abuf, 4096, 1024);

  gemm_bt_k<1><<<dim3(8, 64), 256, 0, stream>>>(gbuf, w2b, d_out, ores, 1024, 4096);
}